// Round 7
// baseline (2493.634 us; speedup 1.0000x reference)
//
#include <hip/hip_runtime.h>
#include <hip/hip_fp8.h>
#include <cstddef>
#include <cstdint>

typedef _Float16 h2v __attribute__((ext_vector_type(2)));
typedef _Float16 h4 __attribute__((ext_vector_type(4)));
typedef _Float16 h8 __attribute__((ext_vector_type(8)));
typedef float    f4 __attribute__((ext_vector_type(4)));
typedef unsigned u4v __attribute__((ext_vector_type(4)));

#define NN      50000
#define IND     512
#define HIDN    256
#define E2P     400000
#define EDD     800000
#define NBLK    196   // ceil(NN/256)
#define PBLK    1563  // ceil(E2P/256)

// ---- workspace layout (bytes) ----
#define OFF_HF16    ((size_t)0)            // 25.6 MB f16 h [NN][256] (dead after k_logits)
#define OFF_H8Q     ((size_t)25600000)     // 12.8 MB fp8 h, ktg-grouped layout (dead after k_edge)
#define OFF_LOGPHI  ((size_t)38400000)     //  1.6 MB f32 [NN][8]
#define OFF_DEG     ((size_t)40000000)     //  int [NN] directed out-degree
#define OFF_LOGDEG  ((size_t)40200000)
#define OFF_DEGC    ((size_t)40400000)
#define OFF_PDEG    ((size_t)40600000)     //  int [NN] pairs-with-src-s count
#define OFF_PBASE   ((size_t)40800000)
#define OFF_PCNT    ((size_t)41000000)
#define OFF_BLK     ((size_t)41200000)     //  4 KB
#define OFF_WT      ((size_t)41204096)     //  256 KB f16 enc_w1^T
#define OFF_BT      ((size_t)41466240)     //  68 KB f16 edge_w1 perm^T
#define OFF_RS      ((size_t)41535872)     //  512 B f32 Rs[64] + alpha at [64]
#define OFF_WSYM    ((size_t)41536384)     //  1.6 MB f32 [E2P] (pair order)
#define OFF_PPOS    ((size_t)43136384)     //  1.6 MB int [E2P] sorted slot of pair
#define OFF_SS      ((size_t)44736384)     //  1.6 MB int [E2P] s per sorted slot
#define OFF_DD      ((size_t)46336384)     //  1.6 MB int [E2P] d per sorted slot
#define OFF_WNP     ((size_t)47936384)     //  3.2 MB float2 [E2P] {w, nrm}
#define OFF_MP      ((size_t)51136384)     // 12.8 MB f16 [E2P][16] (dir0 | dir1), in-place
#define OFF_SA      ((size_t)63936384)     //  1.6 MB f32 [NN][8] raw sum_in
#define OFF_SB      ((size_t)65536384)     //  1.6 MB
#define WS_NEED     ((size_t)67136384)

__device__ inline unsigned char f32_to_fp8(float v) {
    __hip_fp8_e4m3 t(v);
    return (unsigned char)t.__x;
}
__device__ inline h2v u32_as_h2(unsigned u) { union { unsigned u; h2v h; } c; c.u = u; return c.h; }
__device__ inline unsigned h2_as_u32(h2v h) { union { unsigned u; h2v h; } c; c.h = h; return c.u; }

// ---------------- degree count (directed, for logdeg/degc) ----------------
__global__ void k_deg(const int* __restrict__ ei, int* __restrict__ deg) {
    int e = blockIdx.x * 256 + threadIdx.x;   // grid exact: EDD
    atomicAdd(&deg[ei[e]], 1);
}

__global__ void k_node(const int* __restrict__ deg, float* __restrict__ logdeg,
                       float* __restrict__ degc) {
    int n = blockIdx.x * 256 + threadIdx.x;
    if (n < NN) {
        float d = (float)deg[n];
        logdeg[n] = logf(d + 1.0f);
        degc[n]   = fmaxf(d, 1.0f);
    }
}

// ---------------- pair sort by s = ei[p] ----------------
__global__ void k_pdeg(const int* __restrict__ ei, int* __restrict__ pdeg) {
    int p = blockIdx.x * 256 + threadIdx.x;
    if (p < E2P) atomicAdd(&pdeg[ei[p]], 1);
}

__global__ void k_scan1(const int* __restrict__ deg, int* __restrict__ incl,
                        int* __restrict__ blk) {
    __shared__ int sm[256];
    int i = blockIdx.x * 256 + threadIdx.x;
    int v = (i < NN) ? deg[i] : 0;
    sm[threadIdx.x] = v;
    __syncthreads();
    for (int off = 1; off < 256; off <<= 1) {
        int t = (threadIdx.x >= off) ? sm[threadIdx.x - off] : 0;
        __syncthreads();
        sm[threadIdx.x] += t;
        __syncthreads();
    }
    if (i < NN) incl[i] = sm[threadIdx.x];
    if (threadIdx.x == 255) blk[blockIdx.x] = sm[255];
}

__global__ void k_scan2(int* __restrict__ blk) {
    __shared__ int sm[256];
    int v = (threadIdx.x < NBLK) ? blk[threadIdx.x] : 0;
    sm[threadIdx.x] = v;
    __syncthreads();
    for (int off = 1; off < 256; off <<= 1) {
        int t = (threadIdx.x >= off) ? sm[threadIdx.x - off] : 0;
        __syncthreads();
        sm[threadIdx.x] += t;
        __syncthreads();
    }
    if (threadIdx.x < NBLK) blk[threadIdx.x] = sm[threadIdx.x];
}

__global__ void k_scan3(const int* __restrict__ incl, const int* __restrict__ deg,
                        const int* __restrict__ blk, int* __restrict__ base) {
    int i = blockIdx.x * 256 + threadIdx.x;
    if (i < NN) {
        int off = (blockIdx.x > 0) ? blk[blockIdx.x - 1] : 0;
        base[i] = off + incl[i] - deg[i];
    }
}

__global__ void k_ppos(const int* __restrict__ ei, const int* __restrict__ base,
                       int* __restrict__ cnt, int* __restrict__ ppos) {
    int p = blockIdx.x * 256 + threadIdx.x;
    if (p < E2P) {
        int sn = ei[p];
        ppos[p] = base[sn] + atomicAdd(&cnt[sn], 1);
    }
}

// one-time fill of sorted-pair constants (after k_edge produced wsym)
__global__ void k_pfill(const int* __restrict__ ei, const int* __restrict__ ppos,
                        const float* __restrict__ wsym, const float* __restrict__ degc,
                        int* __restrict__ ss, int* __restrict__ dd,
                        float2* __restrict__ wnp) {
    int p = blockIdx.x * 256 + threadIdx.x;
    if (p >= E2P) return;
    int t = ppos[p];
    int s = ei[p], d = ei[EDD + p];
    ss[t] = s;
    dd[t] = d;
    wnp[t] = make_float2(wsym[p], rsqrtf(degc[s] * degc[d]));
}

// ---------------- weight prep ----------------
__global__ void k_prep(const float* __restrict__ enc_w1, const float* __restrict__ edge_w1,
                       const float* __restrict__ R_raw, const float* __restrict__ Rsl,
                       const float* __restrict__ mlog,
                       _Float16* __restrict__ Wt, _Float16* __restrict__ Bt,
                       float* __restrict__ Rs) {
    int gid = blockIdx.x * 256 + threadIdx.x;
    if (gid < 256 * 512) {                       // Wt[n][k] = enc_w1[k][n]
        int n = gid >> 9, k = gid & 511;
        Wt[n * 512 + k] = (_Float16)enc_w1[k * 256 + n];
        return;
    }
    int g2 = gid - 256 * 512;
    if (g2 < 64 * 544) {                         // Bt[n][k'] with interleaved K perm
        int n = g2 / 544, k = g2 - n * 544;
        float v = 0.0f;
        if (k < 512) {
            int orig = (k & 1) ? 256 + (k >> 1) : (k >> 1);
            v = edge_w1[orig * 64 + n];
        } else if (k < 514) {
            v = edge_w1[k * 64 + n];
        }
        Bt[n * 544 + k] = (_Float16)v;
        return;
    }
    int g3 = g2 - 64 * 544;
    if (g3 < 64) {
        int c = g3 >> 3, d = g3 & 7;
        float rv = 0.5f * (R_raw[c * 8 + d] + R_raw[d * 8 + c]);
        float s  = log1pf(expf(Rsl[0])) + 1e-6f;
        Rs[g3] = s * tanhf(rv);
        return;
    }
    if (g3 == 64) {
        Rs[64] = 1.5f / (1.0f + expf(-mlog[0]));
    }
}

// ---------------- encoder layer 1 (f16 MFMA) + fp8 shadow (ktg-grouped layout) ----------------
// h8q row layout: offset = ktg*64 + q*16 + kti*4 + u  for feature kt*16+q*4+u, kt=ktg*4+kti
__global__ __launch_bounds__(256) void k_enc(const float* __restrict__ x,
                                             const _Float16* __restrict__ Wt,
                                             const float* __restrict__ b1,
                                             _Float16* __restrict__ hf,
                                             unsigned char* __restrict__ h8q) {
    __shared__ _Float16 XL[64 * 40];
    __shared__ _Float16 WL[256 * 40];
    const int tid = threadIdx.x;
    const int wid = tid >> 6;
    const int lane = tid & 63;
    const int l15 = lane & 15;
    const int q = lane >> 4;
    const int m0 = blockIdx.x * 64;

    f4 acc[16];
#pragma unroll
    for (int i = 0; i < 16; i++) acc[i] = (f4){0.f, 0.f, 0.f, 0.f};

    const int xr = tid >> 2;
    const int xs = tid & 3;
    const int gr = m0 + xr;

    for (int kt = 0; kt < 16; kt++) {
        __syncthreads();
        f4 xv0 = (f4){0, 0, 0, 0}, xv1 = (f4){0, 0, 0, 0};
        if (gr < NN) {
            const f4* xp = (const f4*)(x + (size_t)gr * IND + kt * 32 + xs * 8);
            xv0 = xp[0]; xv1 = xp[1];
        }
        h8 xh;
#pragma unroll
        for (int u = 0; u < 4; u++) { xh[u] = (_Float16)xv0[u]; xh[4 + u] = (_Float16)xv1[u]; }
        *(h8*)&XL[xr * 40 + xs * 8] = xh;
#pragma unroll
        for (int rep = 0; rep < 4; rep++) {
            int cid = rep * 256 + tid;
            int n = cid >> 2;
            int off = (cid & 3) * 8;
            h8 wv = *(const h8*)(Wt + (size_t)n * IND + kt * 32 + off);
            *(h8*)&WL[n * 40 + off] = wv;
        }
        __syncthreads();
        h8 a = *(const h8*)&XL[(wid * 16 + l15) * 40 + q * 8];
#pragma unroll
        for (int nt = 0; nt < 16; nt++) {
            h8 b = *(const h8*)&WL[(nt * 16 + l15) * 40 + q * 8];
            acc[nt] = __builtin_amdgcn_mfma_f32_16x16x32_f16(a, b, acc[nt], 0, 0, 0);
        }
    }
    const int qf = l15 >> 2;       // q-group of col
    const int uu = l15 & 3;        // u within group
#pragma unroll
    for (int nt = 0; nt < 16; nt++) {
        int col = nt * 16 + l15;
        float bv = b1[col];
        int off8 = (nt >> 2) * 64 + qf * 16 + (nt & 3) * 4 + uu;  // ktg*64+q*16+kti*4+u
#pragma unroll
        for (int reg = 0; reg < 4; reg++) {
            int row = m0 + wid * 16 + q * 4 + reg;
            if (row < NN) {
                float v = fmaxf(acc[nt][reg] + bv, 0.f);
                hf[(size_t)row * HIDN + col] = (_Float16)v;
                h8q[(size_t)row * HIDN + off8] = f32_to_fp8(v);
            }
        }
    }
}

// ---------------- encoder layer 2 + log_softmax ----------------
__global__ void k_logits(const _Float16* __restrict__ hf, const float* __restrict__ w2,
                         const float* __restrict__ b2, float* __restrict__ log_phi) {
    __shared__ float w2L[2048];
    for (int i = threadIdx.x; i < 2048; i += 256) w2L[i] = w2[i];
    __syncthreads();
    int n = blockIdx.x * 256 + threadIdx.x;
    if (n >= NN) return;
    float sum[8];
#pragma unroll
    for (int c = 0; c < 8; c++) sum[c] = b2[c];
    for (int kb = 0; kb < 32; kb++) {
        h8 hv = *(const h8*)(hf + (size_t)n * HIDN + kb * 8);
#pragma unroll
        for (int u = 0; u < 8; u++) {
            float hx = (float)hv[u];
            const float* wr = &w2L[(kb * 8 + u) * 8];
#pragma unroll
            for (int c = 0; c < 8; c++) sum[c] += hx * wr[c];
        }
    }
    float mx = sum[0];
#pragma unroll
    for (int c = 1; c < 8; c++) mx = fmaxf(mx, sum[c]);
    float se = 0.f;
#pragma unroll
    for (int c = 0; c < 8; c++) se += __expf(sum[c] - mx);
    float lse = __logf(se);
#pragma unroll
    for (int c = 0; c < 8; c++) log_phi[(size_t)n * 8 + c] = sum[c] - mx - lse;
}

// ---------------- edge MLP: 64B-sector fp8 gathers (4 q-lanes coalesce per row) ----------------
__global__ __launch_bounds__(256) void k_edge(const int* __restrict__ ei,
        const unsigned char* __restrict__ h8q, const float* __restrict__ logdeg,
        const _Float16* __restrict__ BtG, const float* __restrict__ eb1,
        const float* __restrict__ ew2, const float* __restrict__ eb2,
        float* __restrict__ wsym) {
    __shared__ _Float16 BtL[64 * 168];
    const int tid = threadIdx.x;
    const int wid = tid >> 6;
    const int lane = tid & 63;
    const int l15 = lane & 15;
    const int q = lane >> 4;
    const int eb = blockIdx.x * 256;

    int sidx[4], didx[4];
    float la[4], lb[4];
#pragma unroll
    for (int mt = 0; mt < 4; mt++) {
        int e = eb + wid * 64 + mt * 16 + l15;
        int ee = (e < E2P) ? e : 0;
        sidx[mt] = ei[ee];
        didx[mt] = ei[EDD + ee];
        la[mt] = logdeg[sidx[mt]];
        lb[mt] = logdeg[didx[mt]];
    }

    f4 acc[4][4];
#pragma unroll
    for (int a = 0; a < 4; a++)
#pragma unroll
        for (int b = 0; b < 4; b++) acc[a][b] = (f4){0.f, 0.f, 0.f, 0.f};

    const unsigned char* hq = h8q + q * 16;
    u4v curS[4], curD[4];
#pragma unroll
    for (int mt = 0; mt < 4; mt++) {            // ktg=0: 16B covering kt 0..3 for this q
        curS[mt] = *(const u4v*)(hq + (size_t)sidx[mt] * HIDN);
        curD[mt] = *(const u4v*)(hq + (size_t)didx[mt] * HIDN);
    }
    const h2v sc = (h2v){(_Float16)256.0f, (_Float16)256.0f};

    for (int ph = 0; ph < 4; ph++) {
        const int kbase = ph * 128;
        const int nch = (ph == 3) ? 20 : 16;
        __syncthreads();
        {
            const int r = tid & 63;
            const int cb = tid >> 6;
            for (int ck = cb; ck < nch; ck += 4) {
                h8 v = *(const h8*)(BtG + (size_t)r * 544 + kbase + ck * 8);
                *(h8*)&BtL[r * 168 + ck * 8] = v;
            }
        }
        __syncthreads();
        u4v nS[4], nD[4];
        if (ph < 3) {                           // prefetch next ktg (64B sector per row)
            const int o = (ph + 1) * 64;
#pragma unroll
            for (int mt = 0; mt < 4; mt++) {
                nS[mt] = *(const u4v*)(hq + (size_t)sidx[mt] * HIDN + o);
                nD[mt] = *(const u4v*)(hq + (size_t)didx[mt] * HIDN + o);
            }
        }
#pragma unroll
        for (int kti = 0; kti < 4; kti++) {
            const int kt = ph * 4 + kti;
            h8 af[4];
#pragma unroll
            for (int mt = 0; mt < 4; mt++) {
                unsigned vs = curS[mt][kti], vd = curD[mt][kti];
                h2v sE = u32_as_h2((vs & 0x007f007fu) << 7) * sc;
                h2v sO = u32_as_h2(((vs >> 8) & 0x007f007fu) << 7) * sc;
                h2v dE = u32_as_h2((vd & 0x007f007fu) << 7) * sc;
                h2v dO = u32_as_h2(((vd >> 8) & 0x007f007fu) << 7) * sc;
                h2v pE = sE * dE, pO = sO * dO;
                h2v qE = u32_as_h2(h2_as_u32(sE - dE) & 0x7fff7fffu);
                h2v qO = u32_as_h2(h2_as_u32(sO - dO) & 0x7fff7fffu);
                h8 a;
                a[0] = pE[0]; a[1] = qE[0]; a[2] = pO[0]; a[3] = qO[0];
                a[4] = pE[1]; a[5] = qE[1]; a[6] = pO[1]; a[7] = qO[1];
                af[mt] = a;
            }
            const int ko = kt * 32 - kbase + q * 8;
            h8 bf[4];
#pragma unroll
            for (int nt = 0; nt < 4; nt++)
                bf[nt] = *(const h8*)&BtL[(nt * 16 + l15) * 168 + ko];
#pragma unroll
            for (int mt = 0; mt < 4; mt++)
#pragma unroll
                for (int nt = 0; nt < 4; nt++)
                    acc[mt][nt] = __builtin_amdgcn_mfma_f32_16x16x32_f16(af[mt], bf[nt], acc[mt][nt], 0, 0, 0);
        }
        if (ph == 3) {                          // struct features kt=16 (slab offset 128)
            h8 bf[4];
#pragma unroll
            for (int nt = 0; nt < 4; nt++)
                bf[nt] = *(const h8*)&BtL[(nt * 16 + l15) * 168 + 128 + q * 8];
#pragma unroll
            for (int mt = 0; mt < 4; mt++) {
                h8 a = (h8){0, 0, 0, 0, 0, 0, 0, 0};
                if (q == 0) {
                    a[0] = (_Float16)(la[mt] + lb[mt]);
                    a[1] = (_Float16)fabsf(la[mt] - lb[mt]);
                }
#pragma unroll
                for (int nt = 0; nt < 4; nt++)
                    acc[mt][nt] = __builtin_amdgcn_mfma_f32_16x16x32_f16(a, bf[nt], acc[mt][nt], 0, 0, 0);
            }
        } else {
#pragma unroll
            for (int mt = 0; mt < 4; mt++) { curS[mt] = nS[mt]; curD[mt] = nD[mt]; }
        }
    }

    float b1v[4], w2v[4];
#pragma unroll
    for (int nt = 0; nt < 4; nt++) {
        int col = nt * 16 + l15;
        b1v[nt] = eb1[col];
        w2v[nt] = ew2[col];
    }
    const float b2s = eb2[0];
    float part[4][4];
#pragma unroll
    for (int mt = 0; mt < 4; mt++)
#pragma unroll
        for (int reg = 0; reg < 4; reg++) {
            float s = 0.f;
#pragma unroll
            for (int nt = 0; nt < 4; nt++) {
                float v = acc[mt][nt][reg] + b1v[nt];
                s += fmaxf(v, 0.f) * w2v[nt];
            }
            part[mt][reg] = s;
        }
#pragma unroll
    for (int off = 1; off < 16; off <<= 1)
#pragma unroll
        for (int mt = 0; mt < 4; mt++)
#pragma unroll
            for (int reg = 0; reg < 4; reg++)
                part[mt][reg] += __shfl_xor(part[mt][reg], off, 64);
    if (l15 == 0) {
#pragma unroll
        for (int mt = 0; mt < 4; mt++)
#pragma unroll
            for (int reg = 0; reg < 4; reg++) {
                int er = eb + wid * 64 + mt * 16 + q * 4 + reg;
                if (er < E2P) {
                    float xr = part[mt][reg] + b2s;
                    wsym[er] = 0.8f / (1.0f + __expf(-xr));
                }
            }
    }
}

// ======== BP: pair-ordered (sorted by s), fused, zero edge-permutation ========

// init: m0/m1 = softmax(log_phi[s/d]); contributions into S
__global__ __launch_bounds__(256) void k_initP(const int* __restrict__ ss,
        const int* __restrict__ dd, const float2* __restrict__ wnp,
        const float* __restrict__ Rs, const float* __restrict__ log_phi,
        _Float16* __restrict__ mp, float* __restrict__ S) {
    __shared__ float RsL[64];
    __shared__ float lfL[256][8];
    __shared__ int ssL[256];
    const int tid = threadIdx.x;
    if (tid < 64) RsL[tid] = Rs[tid];
    __syncthreads();
    int t = blockIdx.x * 256 + tid;
    bool valid = t < E2P;
    int tt = valid ? t : 0;
    int s = ss[tt], d = dd[tt];
    float2 wn = wnp[tt];
    ssL[tid] = valid ? s : -1;
    const f4* lps = (const f4*)(log_phi + (size_t)s * 8);
    const f4* lpd = (const f4*)(log_phi + (size_t)d * 8);
    f4 a0 = lps[0], a1 = lps[1], b0 = lpd[0], b1 = lpd[1];
    float ls[8], ld[8];
#pragma unroll
    for (int u = 0; u < 4; u++) { ls[u] = a0[u]; ls[4+u] = a1[u]; ld[u] = b0[u]; ld[4+u] = b1[u]; }
    float m0[8], m1[8];
    {
        float mx = ls[0], mx2 = ld[0];
#pragma unroll
        for (int c = 1; c < 8; c++) { mx = fmaxf(mx, ls[c]); mx2 = fmaxf(mx2, ld[c]); }
        float su = 0.f, su2 = 0.f;
#pragma unroll
        for (int c = 0; c < 8; c++) { m0[c] = __expf(ls[c] - mx); su += m0[c];
                                      m1[c] = __expf(ld[c] - mx2); su2 += m1[c]; }
        float r1 = 1.f / su, r2 = 1.f / su2;
#pragma unroll
        for (int c = 0; c < 8; c++) { m0[c] *= r1; m1[c] *= r2; }
    }
    if (valid) {
        h8 v0, v1;
#pragma unroll
        for (int c = 0; c < 8; c++) { v0[c] = (_Float16)m0[c]; v1[c] = (_Float16)m1[c]; }
        *(h8*)(mp + (size_t)t * 16)     = v0;
        *(h8*)(mp + (size_t)t * 16 + 8) = v1;
    }
    float fe[8], fr[8];
#pragma unroll
    for (int c = 0; c < 8; c++) { fe[c] = 0.f; fr[c] = 0.f; }
#pragma unroll
    for (int c = 0; c < 8; c++)
#pragma unroll
        for (int k = 0; k < 8; k++) {
            float kv = __expf(wn.x * RsL[c * 8 + k]);
            fe[k] += m0[c] * kv;   // s->d, into d
            fr[k] += m1[c] * kv;   // d->s, into s
        }
    float lfe[8];
#pragma unroll
    for (int k = 0; k < 8; k++) {
        lfe[k] = __logf(fmaxf(fe[k], 1e-12f)) * wn.y;
        lfL[tid][k] = __logf(fmaxf(fr[k], 1e-12f)) * wn.y;
    }
    if (valid) {
#pragma unroll
        for (int k = 0; k < 8; k++) atomicAdd(&S[(size_t)d * 8 + k], lfe[k]);
    }
    __syncthreads();
    if (valid && (tid == 0 || ssL[tid - 1] != s)) {
        float acc[8];
#pragma unroll
        for (int k = 0; k < 8; k++) acc[k] = lfL[tid][k];
        int j = tid + 1;
        while (j < 256 && ssL[j] == s) {
#pragma unroll
            for (int k = 0; k < 8; k++) acc[k] += lfL[j][k];
            j++;
        }
#pragma unroll
        for (int k = 0; k < 8; k++) atomicAdd(&S[(size_t)s * 8 + k], acc[k]);
    }
}

// fused BP step: update both directions of pair in place; scatter new contributions into Sn
__global__ __launch_bounds__(256) void k_bpP(const int* __restrict__ ss,
        const int* __restrict__ dd, const float2* __restrict__ wnp,
        const float* __restrict__ Rs, const float* __restrict__ log_phi,
        const float* __restrict__ S, _Float16* __restrict__ mp,
        float* __restrict__ Sn) {
    __shared__ float RsL[64];
    __shared__ float lfL[256][8];
    __shared__ int ssL[256];
    const int tid = threadIdx.x;
    if (tid < 64) RsL[tid] = Rs[tid];
    __syncthreads();
    int t = blockIdx.x * 256 + tid;
    bool valid = t < E2P;
    int tt = valid ? t : 0;
    int s = ss[tt], d = dd[tt];
    float2 wn = wnp[tt];
    ssL[tid] = valid ? s : -1;
    const float alpha = Rs[64];
    h8 v0 = *(const h8*)(mp + (size_t)tt * 16);
    h8 v1 = *(const h8*)(mp + (size_t)tt * 16 + 8);
    float m0[8], m1[8];
#pragma unroll
    for (int c = 0; c < 8; c++) { m0[c] = (float)v0[c]; m1[c] = (float)v1[c]; }
    // exclusion pass: f from current m (K recomputed, shared by both dirs)
    float fe[8], fr[8];
#pragma unroll
    for (int c = 0; c < 8; c++) { fe[c] = 0.f; fr[c] = 0.f; }
#pragma unroll
    for (int c = 0; c < 8; c++)
#pragma unroll
        for (int k = 0; k < 8; k++) {
            float kv = __expf(wn.x * RsL[c * 8 + k]);
            fe[k] += m0[c] * kv;
            fr[k] += m1[c] * kv;
        }
    const f4* lps = (const f4*)(log_phi + (size_t)s * 8);
    const f4* lpd = (const f4*)(log_phi + (size_t)d * 8);
    const f4* Ssp = (const f4*)(S + (size_t)s * 8);
    const f4* Sdp = (const f4*)(S + (size_t)d * 8);
    f4 a0 = lps[0], a1 = lps[1], b0 = lpd[0], b1 = lpd[1];
    f4 c0 = Ssp[0], c1 = Ssp[1], d0 = Sdp[0], d1 = Sdp[1];
    float te[8], tr[8];
#pragma unroll
    for (int u = 0; u < 4; u++) {
        te[u]     = a0[u] + alpha * (c0[u] - __logf(fmaxf(fr[u], 1e-12f)) * wn.y);
        te[4 + u] = a1[u] + alpha * (c1[u] - __logf(fmaxf(fr[4 + u], 1e-12f)) * wn.y);
        tr[u]     = b0[u] + alpha * (d0[u] - __logf(fmaxf(fe[u], 1e-12f)) * wn.y);
        tr[4 + u] = b1[u] + alpha * (d1[u] - __logf(fmaxf(fe[4 + u], 1e-12f)) * wn.y);
    }
    // softmax + damp + renorm (both dirs)
    {
        float mx = te[0], mx2 = tr[0];
#pragma unroll
        for (int c = 1; c < 8; c++) { mx = fmaxf(mx, te[c]); mx2 = fmaxf(mx2, tr[c]); }
        float su = 0.f, su2 = 0.f;
        float e0[8], e1[8];
#pragma unroll
        for (int c = 0; c < 8; c++) { e0[c] = __expf(te[c] - mx); su += e0[c];
                                      e1[c] = __expf(tr[c] - mx2); su2 += e1[c]; }
        float r1 = 0.2f / su, r2 = 0.2f / su2;
        float t1 = 0.f, t2 = 0.f;
#pragma unroll
        for (int c = 0; c < 8; c++) {
            m0[c] = fmaxf(0.8f * m0[c] + e0[c] * r1, 1e-12f); t1 += m0[c];
            m1[c] = fmaxf(0.8f * m1[c] + e1[c] * r2, 1e-12f); t2 += m1[c];
        }
        float q1 = 1.f / t1, q2 = 1.f / t2;
#pragma unroll
        for (int c = 0; c < 8; c++) { m0[c] *= q1; m1[c] *= q2; }
    }
    if (valid) {
        h8 w0, w1;
#pragma unroll
        for (int c = 0; c < 8; c++) { w0[c] = (_Float16)m0[c]; w1[c] = (_Float16)m1[c]; }
        *(h8*)(mp + (size_t)t * 16)     = w0;
        *(h8*)(mp + (size_t)t * 16 + 8) = w1;
    }
    // new contributions from updated m
    float ge[8], gr[8];
#pragma unroll
    for (int c = 0; c < 8; c++) { ge[c] = 0.f; gr[c] = 0.f; }
#pragma unroll
    for (int c = 0; c < 8; c++)
#pragma unroll
        for (int k = 0; k < 8; k++) {
            float kv = __expf(wn.x * RsL[c * 8 + k]);
            ge[k] += m0[c] * kv;
            gr[k] += m1[c] * kv;
        }
    float lge[8];
#pragma unroll
    for (int k = 0; k < 8; k++) {
        lge[k] = __logf(fmaxf(ge[k], 1e-12f)) * wn.y;
        lfL[tid][k] = __logf(fmaxf(gr[k], 1e-12f)) * wn.y;
    }
    if (valid) {
#pragma unroll
        for (int k = 0; k < 8; k++) atomicAdd(&Sn[(size_t)d * 8 + k], lge[k]);
    }
    __syncthreads();
    if (valid && (tid == 0 || ssL[tid - 1] != s)) {
        float acc[8];
#pragma unroll
        for (int k = 0; k < 8; k++) acc[k] = lfL[tid][k];
        int j = tid + 1;
        while (j < 256 && ssL[j] == s) {
#pragma unroll
            for (int k = 0; k < 8; k++) acc[k] += lfL[j][k];
            j++;
        }
#pragma unroll
        for (int k = 0; k < 8; k++) atomicAdd(&Sn[(size_t)s * 8 + k], acc[k]);
    }
}

// ---------------- beliefs = softmax(log_phi + alpha*S) ----------------
__global__ void k_bel(const float* __restrict__ log_phi, const float* __restrict__ S,
                      const float* __restrict__ Rs, float* __restrict__ out) {
    int tid = blockIdx.x * 256 + threadIdx.x;
    if (tid >= NN * 8) return;
    float v = log_phi[tid] + Rs[64] * S[tid];
    float mx = v;
    mx = fmaxf(mx, __shfl_xor(mx, 1, 64));
    mx = fmaxf(mx, __shfl_xor(mx, 2, 64));
    mx = fmaxf(mx, __shfl_xor(mx, 4, 64));
    float ex = __expf(v - mx);
    float s = ex;
    s += __shfl_xor(s, 1, 64); s += __shfl_xor(s, 2, 64); s += __shfl_xor(s, 4, 64);
    out[tid] = ex / s;
}

extern "C" void kernel_launch(void* const* d_in, const int* in_sizes, int n_in,
                              void* d_out, int out_size, void* d_ws, size_t ws_size,
                              hipStream_t stream) {
    if (ws_size < WS_NEED) return;
    const float* x        = (const float*)d_in[0];
    const int*   ei       = (const int*)d_in[1];
    const float* enc_w1   = (const float*)d_in[3];
    const float* enc_b1   = (const float*)d_in[4];
    const float* enc_w2   = (const float*)d_in[5];
    const float* enc_b2   = (const float*)d_in[6];
    const float* edge_w1  = (const float*)d_in[7];
    const float* edge_b1  = (const float*)d_in[8];
    const float* edge_w2  = (const float*)d_in[9];
    const float* edge_b2  = (const float*)d_in[10];
    const float* R_raw    = (const float*)d_in[11];
    const float* Rsl      = (const float*)d_in[12];
    const float* mlog     = (const float*)d_in[13];

    char* ws = (char*)d_ws;
    _Float16* hf     = (_Float16*)(ws + OFF_HF16);
    unsigned char* h8q = (unsigned char*)(ws + OFF_H8Q);
    float* log_phi   = (float*)(ws + OFF_LOGPHI);
    int*   deg       = (int*)  (ws + OFF_DEG);
    float* logdeg    = (float*)(ws + OFF_LOGDEG);
    float* degc      = (float*)(ws + OFF_DEGC);
    int*   pdeg      = (int*)  (ws + OFF_PDEG);
    int*   pbase     = (int*)  (ws + OFF_PBASE);
    int*   pcnt      = (int*)  (ws + OFF_PCNT);
    int*   blk       = (int*)  (ws + OFF_BLK);
    _Float16* Wt     = (_Float16*)(ws + OFF_WT);
    _Float16* Bt     = (_Float16*)(ws + OFF_BT);
    float* Rs        = (float*)(ws + OFF_RS);
    float* wsym      = (float*)(ws + OFF_WSYM);
    int*   ppos      = (int*)  (ws + OFF_PPOS);
    int*   ssb      = (int*)  (ws + OFF_SS);
    int*   ddb      = (int*)  (ws + OFF_DD);
    float2* wnp      = (float2*)(ws + OFF_WNP);
    _Float16* mp     = (_Float16*)(ws + OFF_MP);
    float* SA        = (float*)(ws + OFF_SA);
    float* SB        = (float*)(ws + OFF_SB);

    hipMemsetAsync(deg, 0, (size_t)NN * 4, stream);
    hipMemsetAsync(pdeg, 0, (size_t)NN * 4, stream);
    k_deg<<<dim3(EDD / 256), dim3(256), 0, stream>>>(ei, deg);
    k_node<<<dim3(NBLK), dim3(256), 0, stream>>>(deg, logdeg, degc);
    k_prep<<<dim3((256 * 512 + 64 * 544 + 65 + 255) / 256), dim3(256), 0, stream>>>(
        enc_w1, edge_w1, R_raw, Rsl, mlog, Wt, Bt, Rs);
    // pair sort by s (one-time)
    k_pdeg<<<dim3(PBLK), dim3(256), 0, stream>>>(ei, pdeg);
    k_scan1<<<dim3(NBLK), dim3(256), 0, stream>>>(pdeg, pcnt /*incl scratch*/, blk);
    k_scan2<<<dim3(1), dim3(256), 0, stream>>>(blk);
    k_scan3<<<dim3(NBLK), dim3(256), 0, stream>>>(pcnt, pdeg, blk, pbase);
    hipMemsetAsync(pcnt, 0, (size_t)NN * 4, stream);
    k_ppos<<<dim3(PBLK), dim3(256), 0, stream>>>(ei, pbase, pcnt, ppos);
    // encoder + edge MLP
    k_enc<<<dim3((NN + 63) / 64), dim3(256), 0, stream>>>(x, Wt, enc_b1, hf, h8q);
    k_logits<<<dim3(NBLK), dim3(256), 0, stream>>>(hf, enc_w2, enc_b2, log_phi);
    k_edge<<<dim3(PBLK), dim3(256), 0, stream>>>(ei, h8q, logdeg, Bt, edge_b1,
                                                 edge_w2, edge_b2, wsym);
    k_pfill<<<dim3(PBLK), dim3(256), 0, stream>>>(ei, ppos, wsym, degc, ssb, ddb, wnp);
    // BP loop
    hipMemsetAsync(SA, 0, (size_t)NN * 8 * 4, stream);
    k_initP<<<dim3(PBLK), dim3(256), 0, stream>>>(ssb, ddb, wnp, Rs, log_phi, mp, SA);
    float* Sc = SA; float* Sx = SB;
    for (int t = 0; t < 10; t++) {
        hipMemsetAsync(Sx, 0, (size_t)NN * 8 * 4, stream);
        k_bpP<<<dim3(PBLK), dim3(256), 0, stream>>>(ssb, ddb, wnp, Rs, log_phi, Sc, mp, Sx);
        float* tsw = Sc; Sc = Sx; Sx = tsw;
    }
    k_bel<<<dim3((NN * 8 + 255) / 256), dim3(256), 0, stream>>>(log_phi, Sc, Rs,
                                                                (float*)d_out);
    (void)in_sizes; (void)n_in; (void)out_size;
}